// Round 1
// baseline (9365.215 us; speedup 1.0000x reference)
//
#include <hip/hip_runtime.h>
#include <hip/hip_bf16.h>
#include <cstdint>

// ---- problem constants ----
#define TT 512
#define BB 256
#define HID 768
#define INDIM 129
#define INPAD 160
#define OUTD 128

typedef __attribute__((ext_vector_type(8))) short bf16x8;
typedef __attribute__((ext_vector_type(4))) float f32x4;
typedef unsigned short u16;

#define MFMA16(A, B, C) __builtin_amdgcn_mfma_f32_16x16x32_bf16(A, B, C, 0, 0, 0)

__device__ __forceinline__ u16 f2bf(float f) {
  union { float f; unsigned u; } v; v.f = f;
  unsigned u = v.u;
  u += 0x7fffu + ((u >> 16) & 1u);   // round-to-nearest-even
  return (u16)(u >> 16);
}
__device__ __forceinline__ float sigm(float x) { return 1.0f / (1.0f + __expf(-x)); }
__device__ __forceinline__ float tanh_fast(float x) { return 2.0f / (1.0f + __expf(-2.0f * x)) - 1.0f; }

// ---- one-time prep: bf16 weight conversion, bias fuse, state zero ----
__global__ __launch_bounds__(256) void prep_kernel(
    const float* __restrict__ W_ih, const float* __restrict__ W_hh,
    const float* __restrict__ b_ih, const float* __restrict__ b_hh,
    const float* __restrict__ W_dec,
    u16* __restrict__ wWhh, u16* __restrict__ wWih, u16* __restrict__ wWdec,
    float* __restrict__ bias, float* __restrict__ c, u16* __restrict__ h0) {
  int stride = blockDim.x * gridDim.x;
  int i0 = blockIdx.x * blockDim.x + threadIdx.x;
  for (int i = i0; i < 3072 * HID; i += stride) wWhh[i] = f2bf(W_hh[i]);
  for (int i = i0; i < 3072 * INPAD; i += stride) {
    int r = i / INPAD; int k = i - r * INPAD;
    wWih[i] = (k < INDIM) ? f2bf(W_ih[r * INDIM + k]) : (u16)0;
  }
  for (int i = i0; i < OUTD * HID; i += stride) wWdec[i] = f2bf(W_dec[i]);
  for (int i = i0; i < 3072; i += stride) bias[i] = b_ih[i] + b_hh[i];
  for (int i = i0; i < BB * HID; i += stride) { c[i] = 0.0f; h0[i] = (u16)0; }
}

// ---- per-timestep kernel: LSTM step (192 WGs) + fused decode of h_{s-1} (8 WGs) ----
__global__ __launch_bounds__(256) void step_kernel(
    const float* __restrict__ seq, const u16* __restrict__ Wih,
    const u16* __restrict__ Whh, const float* __restrict__ bias,
    const u16* __restrict__ h_cur, u16* __restrict__ h_next,
    float* __restrict__ c, const u16* __restrict__ Wdec,
    const float* __restrict__ bdec, float* __restrict__ out,
    int s, int out_idx, int do_step) {
  __shared__ u16 lds_x[32 * 168];        // x_t tile, bf16, stride 168 (pad)
  __shared__ float lds_g[4 * 32 * 32];   // gate exchange i/f/g/o

  const int tid = threadIdx.x;
  const int w = tid >> 6;                // wave 0..3
  const int lane = tid & 63;
  const int quad = lane >> 4;
  const int l16 = lane & 15;
  const int bid = blockIdx.x;

  const bool is_step = (do_step != 0) && (bid < 192);
  int bt, ct = 0;
  if (is_step) { bt = bid / 24; ct = bid - bt * 24; }
  else         { bt = do_step ? (bid - 192) : bid; }
  const int b0 = bt * 32;

  if (is_step) {
    // zero the pad columns (129..159), fill cols 0..128 from seq (fp32 -> bf16)
    if (tid < 32) {
      for (int k = INDIM; k < INPAD; ++k) lds_x[tid * 168 + k] = (u16)0;
    }
    const float* xt = seq + (size_t)s * (BB * INDIM);
    for (int i = tid; i < 32 * INDIM; i += 256) {
      int r = i / INDIM; int k = i - r * INDIM;
      lds_x[r * 168 + k] = f2bf(xt[(b0 + r) * INDIM + k]);
    }
  }
  __syncthreads();

  f32x4 acc[2][2];
  for (int mt = 0; mt < 2; ++mt)
    for (int nt = 0; nt < 2; ++nt)
      acc[mt][nt] = (f32x4){0.f, 0.f, 0.f, 0.f};

  if (is_step) {
    const int hc0 = ct * 32;
    const int grow = w * HID + hc0;      // this wave's base gate-row in W
    // --- recurrent part: K = 768 over W_hh, A = h_cur (global, L2-hot) ---
    #pragma unroll 6
    for (int k = 0; k < HID; k += 32) {
      const int ko = k + quad * 8;
      bf16x8 a0 = *(const bf16x8*)&h_cur[(size_t)(b0 + l16) * HID + ko];
      bf16x8 a1 = *(const bf16x8*)&h_cur[(size_t)(b0 + 16 + l16) * HID + ko];
      const u16* wp = Whh + (size_t)(grow + l16) * HID + ko;
      bf16x8 bb0 = *(const bf16x8*)wp;
      bf16x8 bb1 = *(const bf16x8*)(wp + 16 * HID);
      acc[0][0] = MFMA16(a0, bb0, acc[0][0]);
      acc[1][0] = MFMA16(a1, bb0, acc[1][0]);
      acc[0][1] = MFMA16(a0, bb1, acc[0][1]);
      acc[1][1] = MFMA16(a1, bb1, acc[1][1]);
    }
    // --- input part: K = 160 (padded) over W_ih, A = x_t (LDS) ---
    #pragma unroll
    for (int k = 0; k < INPAD; k += 32) {
      const int ko = k + quad * 8;
      bf16x8 a0 = *(const bf16x8*)&lds_x[l16 * 168 + ko];
      bf16x8 a1 = *(const bf16x8*)&lds_x[(16 + l16) * 168 + ko];
      const u16* wp = Wih + (size_t)(grow + l16) * INPAD + ko;
      bf16x8 bb0 = *(const bf16x8*)wp;
      bf16x8 bb1 = *(const bf16x8*)(wp + 16 * INPAD);
      acc[0][0] = MFMA16(a0, bb0, acc[0][0]);
      acc[1][0] = MFMA16(a1, bb0, acc[1][0]);
      acc[0][1] = MFMA16(a0, bb1, acc[0][1]);
      acc[1][1] = MFMA16(a1, bb1, acc[1][1]);
    }
    // gate exchange: wave w holds gate w for [32b x 32j]
    for (int mt = 0; mt < 2; ++mt)
      for (int nt = 0; nt < 2; ++nt)
        for (int r = 0; r < 4; ++r) {
          int bl = mt * 16 + quad * 4 + r;
          int jl = nt * 16 + l16;
          lds_g[(w * 32 + bl) * 32 + jl] = acc[mt][nt][r];
        }
    __syncthreads();
    // cell update: 4 cells/thread
    const int bl = tid >> 3;
    const int j0 = (tid & 7) * 4;
    #pragma unroll
    for (int e = 0; e < 4; ++e) {
      int j = j0 + e;
      int gc = hc0 + j;
      float gi = lds_g[(0 * 32 + bl) * 32 + j] + bias[0 * HID + gc];
      float gf = lds_g[(1 * 32 + bl) * 32 + j] + bias[1 * HID + gc];
      float gg = lds_g[(2 * 32 + bl) * 32 + j] + bias[2 * HID + gc];
      float go = lds_g[(3 * 32 + bl) * 32 + j] + bias[3 * HID + gc];
      float iv = sigm(gi), fv = sigm(gf), gv = tanh_fast(gg), ov = sigm(go);
      size_t ci = (size_t)(b0 + bl) * HID + gc;
      float cn = fv * c[ci] + iv * gv;
      c[ci] = cn;
      h_next[ci] = f2bf(ov * tanh_fast(cn));
    }
  } else if (out_idx >= 0) {
    // decode h_{s-1} (= h_cur) -> out[out_idx]; wave w owns out cols w*32..w*32+31
    #pragma unroll 6
    for (int k = 0; k < HID; k += 32) {
      const int ko = k + quad * 8;
      bf16x8 a0 = *(const bf16x8*)&h_cur[(size_t)(b0 + l16) * HID + ko];
      bf16x8 a1 = *(const bf16x8*)&h_cur[(size_t)(b0 + 16 + l16) * HID + ko];
      const u16* wp = Wdec + (size_t)(w * 32 + l16) * HID + ko;
      bf16x8 bb0 = *(const bf16x8*)wp;
      bf16x8 bb1 = *(const bf16x8*)(wp + 16 * HID);
      acc[0][0] = MFMA16(a0, bb0, acc[0][0]);
      acc[1][0] = MFMA16(a1, bb0, acc[1][0]);
      acc[0][1] = MFMA16(a0, bb1, acc[0][1]);
      acc[1][1] = MFMA16(a1, bb1, acc[1][1]);
    }
    float bd0 = bdec[w * 32 + l16];
    float bd1 = bdec[w * 32 + 16 + l16];
    float* ob = out + (size_t)out_idx * (BB * OUTD);
    for (int mt = 0; mt < 2; ++mt)
      for (int nt = 0; nt < 2; ++nt)
        for (int r = 0; r < 4; ++r) {
          int row = b0 + mt * 16 + quad * 4 + r;
          int col = w * 32 + nt * 16 + l16;
          ob[(size_t)row * OUTD + col] = acc[mt][nt][r] + (nt ? bd1 : bd0);
        }
  }
}

extern "C" void kernel_launch(void* const* d_in, const int* in_sizes, int n_in,
                              void* d_out, int out_size, void* d_ws, size_t ws_size,
                              hipStream_t stream) {
  (void)in_sizes; (void)n_in; (void)out_size; (void)ws_size;
  const float* seq   = (const float*)d_in[0];
  const float* W_ih  = (const float*)d_in[1];
  const float* W_hh  = (const float*)d_in[2];
  const float* b_ih  = (const float*)d_in[3];
  const float* b_hh  = (const float*)d_in[4];
  const float* W_dec = (const float*)d_in[5];
  const float* b_dec = (const float*)d_in[6];
  float* out = (float*)d_out;

  // workspace layout (~7.2 MB)
  u16* wsb   = (u16*)d_ws;
  u16* Whh   = wsb;                       // 3072*768 bf16
  u16* Wih   = Whh + 3072 * HID;          // 3072*160 bf16
  u16* Wdec  = Wih + 3072 * INPAD;        // 128*768 bf16
  float* bias = (float*)(Wdec + OUTD * HID);  // 3072 f32
  float* c    = bias + 3072;              // 256*768 f32
  u16* h0     = (u16*)(c + BB * HID);     // 256*768 bf16 (ping)
  u16* h1     = h0 + BB * HID;            // 256*768 bf16 (pong)

  prep_kernel<<<512, 256, 0, stream>>>(W_ih, W_hh, b_ih, b_hh, W_dec,
                                       Whh, Wih, Wdec, bias, c, h0);

  for (int s = 0; s < TT; ++s) {
    const u16* hc = (s & 1) ? h1 : h0;
    u16* hn       = (s & 1) ? h0 : h1;
    int oidx = (s >= 257) ? (s - 257) : -1;   // decode hidden[s-1] (>= index 256)
    int grid = (oidx >= 0) ? 200 : 192;
    step_kernel<<<grid, 256, 0, stream>>>(seq, Wih, Whh, bias, hc, hn, c,
                                          Wdec, b_dec, out, s, oidx, 1);
  }
  // tail: decode hidden[511] (lives in buffer 512&1 == 0) -> out row 255
  step_kernel<<<8, 256, 0, stream>>>(seq, Wih, Whh, bias, h0, h1, c,
                                     Wdec, b_dec, out, 512, 255, 0);
}